// Round 15
// baseline (211.927 us; speedup 1.0000x reference)
//
#include <hip/hip_runtime.h>

#define NN 50000
#define NE 800000
#define HD 128
#define NBK 98     // ceil(NN/512) dst-buckets
#define BCAP 16384 // fixed pairs capacity per bucket
#define FB 196     // fill1 edge blocks (196*4096 >= NE)
#define CVB 200    // x->bf16 convert blocks folded into fill1

using short8 = __attribute__((ext_vector_type(8))) short;
using f32x4  = __attribute__((ext_vector_type(4))) float;

__device__ inline unsigned short rne_bf16(float v) {
    union { float f; unsigned u; } c; c.f = v;
    return (unsigned short)((c.u + 0x7fff + ((c.u >> 16) & 1)) >> 16);
}
__device__ inline float bf16_to_f32(unsigned short h) {
    union { unsigned u; float f; } c; c.u = ((unsigned)h) << 16;
    return c.f;
}

// ---------------- 1: bin edges + prepw + x->bf16 convert (R13-proven) ----------------

__global__ __launch_bounds__(256) void k_fill1(const int* __restrict__ ei,
                                               int* __restrict__ bcur,
                                               int* __restrict__ pairs,
                                               const float* __restrict__ W1,
                                               const float* __restrict__ W2,
                                               unsigned short* __restrict__ hi1,
                                               unsigned short* __restrict__ lo1,
                                               unsigned short* __restrict__ hi2,
                                               unsigned short* __restrict__ lo2,
                                               const float* __restrict__ x,
                                               unsigned short* __restrict__ xb) {
    int t = threadIdx.x, b = blockIdx.x;
    if (b >= FB + 16) {  // ---- x -> bf16 convert path ----
        int bb = b - (FB + 16);
        const int total = NN * HD / 8;
        for (int i = bb * 256 + t; i < total; i += CVB * 256) {
            float4 a0 = ((const float4*)x)[i * 2];
            float4 a1 = ((const float4*)x)[i * 2 + 1];
            short8 r;
            r[0] = (short)rne_bf16(a0.x); r[1] = (short)rne_bf16(a0.y);
            r[2] = (short)rne_bf16(a0.z); r[3] = (short)rne_bf16(a0.w);
            r[4] = (short)rne_bf16(a1.x); r[5] = (short)rne_bf16(a1.y);
            r[6] = (short)rne_bf16(a1.z); r[7] = (short)rne_bf16(a1.w);
            *(short8*)(xb + (size_t)i * 8) = r;
        }
        return;
    }
    if (b >= FB) {  // ---- prepw path ----
        int bb = b - FB;
        const float* W = (bb < 8) ? W1 : W2;
        unsigned short* hi = (bb < 8) ? hi1 : hi2;
        unsigned short* lo = (bb < 8) ? lo1 : lo2;
        int tid = (bb & 7) * 256 + t;
        int lane = tid & 63;
        int ks = (tid >> 6) & 3;
        int nt = tid >> 8;
        int n = nt * 16 + (lane & 15);
        int k0 = ks * 32 + (lane >> 4) * 8;
#pragma unroll
        for (int j = 0; j < 8; ++j) {
            float v = W[(k0 + j) * HD + n];
            unsigned short h = rne_bf16(v);
            float rem = v - bf16_to_f32(h);
            hi[(size_t)tid * 8 + j] = h;
            lo[(size_t)tid * 8 + j] = rne_bf16(rem);
        }
        return;
    }
    // ---- binning path ----
    __shared__ int dr[4096], sc[4096];
    __shared__ int hist[NBK], base[NBK];
    for (int i = t; i < NBK; i += 256) hist[i] = 0;
    __syncthreads();
    int e0 = b * 4096;
#pragma unroll
    for (int u = 0; u < 16; ++u) {
        int idx = u * 256 + t, e = e0 + idx;
        int r = -1, c = 0;
        if (e < NE) {
            r = ei[e];
            c = ei[NE + e];
            atomicAdd(&hist[r >> 9], 1);
        }
        dr[idx] = r;
        sc[idx] = c;
    }
    __syncthreads();
    for (int i = t; i < NBK; i += 256) {
        base[i] = atomicAdd(&bcur[i], hist[i]);
        hist[i] = 0;
    }
    __syncthreads();
#pragma unroll
    for (int u = 0; u < 16; ++u) {
        int idx = u * 256 + t;
        int r = dr[idx];
        if (r >= 0) {
            int bk = r >> 9;
            int pos = atomicAdd(&hist[bk], 1);
            pairs[(size_t)bk * BCAP + base[bk] + pos] = ((r & 511) << 16) | sc[idx];
        }
    }
}

// ---------------- 2: per-bucket finalize (R13-proven) ----------------

__global__ __launch_bounds__(256) void k_fill2(const int* __restrict__ pairs,
                                               const int* __restrict__ bcur,
                                               int* __restrict__ deg,
                                               int* __restrict__ offs,
                                               float* __restrict__ dinv,
                                               int* __restrict__ csr) {
    __shared__ int spart[256];
    __shared__ int cnt[512];
    __shared__ int lcur[512];
    int b = blockIdx.x, t = threadIdx.x;
    int n0 = b * 512;
    int nodes = min(512, NN - n0);

    int v = (t < NBK && t < b) ? bcur[t] : 0;
    spart[t] = v;
    __syncthreads();
#pragma unroll
    for (int o = 128; o > 0; o >>= 1) {
        if (t < o) spart[t] += spart[t + o];
        __syncthreads();
    }
    int base = spart[0];
    int tot = bcur[b];

    for (int i = t; i < 512; i += 256) cnt[i] = 0;
    __syncthreads();
    const int* pp = pairs + (size_t)b * BCAP;
    for (int p = t; p < tot; p += 256) atomicAdd(&cnt[pp[p] >> 16], 1);
    __syncthreads();

    int d0 = (2 * t < nodes) ? cnt[2 * t] : 0;
    int d1 = (2 * t + 1 < nodes) ? cnt[2 * t + 1] : 0;
    spart[t] = d0 + d1;
    __syncthreads();
#pragma unroll
    for (int o = 1; o < 256; o <<= 1) {
        int x = (t >= o) ? spart[t - o] : 0;
        __syncthreads();
        spart[t] += x;
        __syncthreads();
    }
    int excl = spart[t] - (d0 + d1);
    int o0 = base + excl, o1 = o0 + d0;
    if (2 * t < nodes) {
        offs[n0 + 2 * t] = o0;
        lcur[2 * t] = o0;
        deg[n0 + 2 * t] = d0;
        dinv[n0 + 2 * t] = rsqrtf((float)(d0 + 1));
    }
    if (2 * t + 1 < nodes) {
        offs[n0 + 2 * t + 1] = o1;
        lcur[2 * t + 1] = o1;
        deg[n0 + 2 * t + 1] = d1;
        dinv[n0 + 2 * t + 1] = rsqrtf((float)(d1 + 1));
    }
    __syncthreads();

    for (int p = t; p < tot; p += 256) {
        int pr = pp[p];
        int slot = atomicAdd(&lcur[pr >> 16], 1);
        csr[slot] = pr & 0xFFFF;
    }
}

// ---------------- fused agg + MFMA GEMM: 8 waves, 2 nodes/wave interleaved ----------
// phase A: wave w owns rows {2w,2w+1}; both nodes' chains (csr->dinv->gathers)
// issued interleaved -> 8 feature gathers in flight, cross-node latency overlap.
// phase B: wave w computes col-tile nt=w of the 16x128 GEMM from LDS.

template <bool RELU, bool OUTBF16>
__global__ __launch_bounds__(512) void k_agg_gemm(const unsigned short* __restrict__ src,
                                                  const int* __restrict__ csr,
                                                  const int* __restrict__ offs,
                                                  const int* __restrict__ deg,
                                                  const float* __restrict__ dinv,
                                                  const unsigned short* __restrict__ Whi,
                                                  const unsigned short* __restrict__ Wlo,
                                                  const float* __restrict__ bias,
                                                  void* __restrict__ Cout) {
    __shared__ unsigned short As[16 * 128];  // 4KB, rows 256B, XOR-swizzled slots
    int t = threadIdx.x;
    int w = t >> 6, l = t & 63;
    int q = l >> 4, sub = l & 15;
    int n0 = blockIdx.x * 16;

    // ---- phase A: 2 nodes, interleaved chains ----
    int rowA = w * 2, rowB = w * 2 + 1;
    int nodeA = n0 + rowA, nodeB = n0 + rowB;
    int oA = offs[nodeA], oB = offs[nodeB];
    int dgA = deg[nodeA], dgB = deg[nodeB];
    float dA = dinv[nodeA], dB = dinv[nodeB];

    int nA = min(64, dgA), nB = min(64, dgB);
    int mycA = (l < nA) ? csr[oA + l] : nodeA;
    int mycB = (l < nB) ? csr[oB + l] : nodeB;
    float mywA = (l < nA) ? dA * dinv[mycA] : 0.0f;
    float mywB = (l < nB) ? dB * dinv[mycB] : 0.0f;

    float accA[8], accB[8];
    if (q == 0) {
        float sA = dA * dA, sB = dB * dB;
        short8 vA = *(const short8*)(src + (size_t)nodeA * HD + sub * 8);
        short8 vB = *(const short8*)(src + (size_t)nodeB * HD + sub * 8);
#pragma unroll
        for (int k = 0; k < 8; ++k) {
            accA[k] = sA * bf16_to_f32((unsigned short)vA[k]);
            accB[k] = sB * bf16_to_f32((unsigned short)vB[k]);
        }
    } else {
#pragma unroll
        for (int k = 0; k < 8; ++k) { accA[k] = 0.0f; accB[k] = 0.0f; }
    }

    int jmA = (nA + 15) >> 4, jmB = (nB + 15) >> 4;
    int jm = max(jmA, jmB);
    for (int j = 0; j < jm; ++j) {
        int e = j * 16 + q;
        bool doA = (j < jmA), doB = (j < jmB);
        short8 vA0, vA1, vA2, vA3, vB0, vB1, vB2, vB3;
        float wA0, wA1, wA2, wA3, wB0, wB1, wB2, wB3;
        if (doA) {
            int c0 = __shfl(mycA, e), c1 = __shfl(mycA, e + 4);
            int c2 = __shfl(mycA, e + 8), c3 = __shfl(mycA, e + 12);
            wA0 = __shfl(mywA, e); wA1 = __shfl(mywA, e + 4);
            wA2 = __shfl(mywA, e + 8); wA3 = __shfl(mywA, e + 12);
            vA0 = *(const short8*)(src + (size_t)c0 * HD + sub * 8);
            vA1 = *(const short8*)(src + (size_t)c1 * HD + sub * 8);
            vA2 = *(const short8*)(src + (size_t)c2 * HD + sub * 8);
            vA3 = *(const short8*)(src + (size_t)c3 * HD + sub * 8);
        }
        if (doB) {
            int c0 = __shfl(mycB, e), c1 = __shfl(mycB, e + 4);
            int c2 = __shfl(mycB, e + 8), c3 = __shfl(mycB, e + 12);
            wB0 = __shfl(mywB, e); wB1 = __shfl(mywB, e + 4);
            wB2 = __shfl(mywB, e + 8); wB3 = __shfl(mywB, e + 12);
            vB0 = *(const short8*)(src + (size_t)c0 * HD + sub * 8);
            vB1 = *(const short8*)(src + (size_t)c1 * HD + sub * 8);
            vB2 = *(const short8*)(src + (size_t)c2 * HD + sub * 8);
            vB3 = *(const short8*)(src + (size_t)c3 * HD + sub * 8);
        }
        if (doA) {
#pragma unroll
            for (int k = 0; k < 8; ++k) {
                accA[k] = fmaf(wA0, bf16_to_f32((unsigned short)vA0[k]), accA[k]);
                accA[k] = fmaf(wA1, bf16_to_f32((unsigned short)vA1[k]), accA[k]);
                accA[k] = fmaf(wA2, bf16_to_f32((unsigned short)vA2[k]), accA[k]);
                accA[k] = fmaf(wA3, bf16_to_f32((unsigned short)vA3[k]), accA[k]);
            }
        }
        if (doB) {
#pragma unroll
            for (int k = 0; k < 8; ++k) {
                accB[k] = fmaf(wB0, bf16_to_f32((unsigned short)vB0[k]), accB[k]);
                accB[k] = fmaf(wB1, bf16_to_f32((unsigned short)vB1[k]), accB[k]);
                accB[k] = fmaf(wB2, bf16_to_f32((unsigned short)vB2[k]), accB[k]);
                accB[k] = fmaf(wB3, bf16_to_f32((unsigned short)vB3[k]), accB[k]);
            }
        }
    }

    // rare tails: deg > 64 (wave-uniform branches)
    for (int base = 64; base < dgA; base += 64) {
        int n = min(64, dgA - base);
        int myc = (l < n) ? csr[oA + base + l] : nodeA;
        float myw = (l < n) ? dA * dinv[myc] : 0.0f;
        for (int j2 = 0; j2 * 4 < n; ++j2) {
            int c = __shfl(myc, j2 * 4 + q);
            float wg = __shfl(myw, j2 * 4 + q);
            short8 v = *(const short8*)(src + (size_t)c * HD + sub * 8);
#pragma unroll
            for (int k = 0; k < 8; ++k)
                accA[k] = fmaf(wg, bf16_to_f32((unsigned short)v[k]), accA[k]);
        }
    }
    for (int base = 64; base < dgB; base += 64) {
        int n = min(64, dgB - base);
        int myc = (l < n) ? csr[oB + base + l] : nodeB;
        float myw = (l < n) ? dB * dinv[myc] : 0.0f;
        for (int j2 = 0; j2 * 4 < n; ++j2) {
            int c = __shfl(myc, j2 * 4 + q);
            float wg = __shfl(myw, j2 * 4 + q);
            short8 v = *(const short8*)(src + (size_t)c * HD + sub * 8);
#pragma unroll
            for (int k = 0; k < 8; ++k)
                accB[k] = fmaf(wg, bf16_to_f32((unsigned short)v[k]), accB[k]);
        }
    }

#pragma unroll
    for (int k = 0; k < 8; ++k) {
        accA[k] += __shfl_xor(accA[k], 16);
        accA[k] += __shfl_xor(accA[k], 32);
        accB[k] += __shfl_xor(accB[k], 16);
        accB[k] += __shfl_xor(accB[k], 32);
    }
    if (q == 0) {
        short8 rA, rB;
#pragma unroll
        for (int k = 0; k < 8; ++k) {
            rA[k] = (short)rne_bf16(accA[k]);
            rB[k] = (short)rne_bf16(accB[k]);
        }
        int byteA = (sub * 16) ^ ((rowA & 7) << 4);
        int byteB = (sub * 16) ^ ((rowB & 7) << 4);
        *(short8*)((char*)As + rowA * 256 + byteA) = rA;
        *(short8*)((char*)As + rowB * 256 + byteB) = rB;
    }
    __syncthreads();

    // ---- phase B: GEMM 16x128, wave w -> col-tile nt=w ----
    f32x4 cacc = (f32x4){0.f, 0.f, 0.f, 0.f};
    int arow = l & 15;
    int nt = w;
#pragma unroll
    for (int ks = 0; ks < 4; ++ks) {
        int byte = (ks * 64 + (l >> 4) * 16) ^ ((arow & 7) << 4);
        short8 ahi = *(const short8*)((char*)As + arow * 256 + byte);
        size_t fo = ((size_t)(nt * 4 + ks) * 64 + l) * 8;
        short8 bhi = *(const short8*)(Whi + fo);
        short8 blo = *(const short8*)(Wlo + fo);
        cacc = __builtin_amdgcn_mfma_f32_16x16x32_bf16(ahi, bhi, cacc, 0, 0, 0);
        cacc = __builtin_amdgcn_mfma_f32_16x16x32_bf16(ahi, blo, cacc, 0, 0, 0);
    }

    int col = nt * 16 + (l & 15);
    float bv = bias[col];
#pragma unroll
    for (int r = 0; r < 4; ++r) {
        int gr = n0 + (l >> 4) * 4 + r;
        float v = cacc[r] + bv;
        if (RELU) v = fmaxf(v, 0.f);
        if (OUTBF16)
            ((unsigned short*)Cout)[(size_t)gr * HD + col] = rne_bf16(v);
        else
            ((float*)Cout)[(size_t)gr * HD + col] = v;
    }
}

// ---------------- launch ----------------

extern "C" void kernel_launch(void* const* d_in, const int* in_sizes, int n_in,
                              void* d_out, int out_size, void* d_ws, size_t ws_size,
                              hipStream_t stream) {
    const float* x  = (const float*)d_in[0];
    const int*   ei = (const int*)d_in[1];
    const float* W1 = (const float*)d_in[2];
    const float* b1 = (const float*)d_in[3];
    const float* W2 = (const float*)d_in[4];
    const float* b2 = (const float*)d_in[5];
    float* out = (float*)d_out;

    char* ws = (char*)d_ws;
    size_t off = 0;
    auto alloc = [&](size_t bytes) {
        void* p = ws + off;
        off = (off + bytes + 255) & ~(size_t)255;
        return p;
    };
    int*   bcur = (int*)alloc(NBK * 4);  // zeroed by memset
    int*   deg  = (int*)alloc(NN * 4);
    int*   offs = (int*)alloc(NN * 4);
    float* dinv = (float*)alloc(NN * 4);
    int*   csr  = (int*)alloc((size_t)NE * 4);
    unsigned short* xb = (unsigned short*)alloc((size_t)NN * HD * 2);
    // pairs (6.4MB packed) and hb (12.8MB) overlap: pairs dead after fill2
    char* region = (char*)alloc((size_t)NN * HD * 2);
    int*  pairs = (int*)region;
    unsigned short* hb = (unsigned short*)region;
    unsigned short* Whi1 = (unsigned short*)alloc(16384 * 2);
    unsigned short* Wlo1 = (unsigned short*)alloc(16384 * 2);
    unsigned short* Whi2 = (unsigned short*)alloc(16384 * 2);
    unsigned short* Wlo2 = (unsigned short*)alloc(16384 * 2);

    // CSR build + weight prep + x convert
    hipMemsetAsync(bcur, 0, NBK * 4, stream);
    k_fill1<<<FB + 16 + CVB, 256, 0, stream>>>(ei, bcur, pairs, W1, W2,
                                               Whi1, Wlo1, Whi2, Wlo2, x, xb);
    k_fill2<<<NBK, 256, 0, stream>>>(pairs, bcur, deg, offs, dinv, csr);

    // conv1 fused: hb = relu(agg(xb)@W1 + b1) [bf16 out]
    k_agg_gemm<true, true><<<NN / 16, 512, 0, stream>>>(xb, csr, offs, deg, dinv,
                                                        Whi1, Wlo1, b1, hb);
    // conv2 fused: out = agg(hb)@W2 + b2 [fp32 out]
    k_agg_gemm<false, false><<<NN / 16, 512, 0, stream>>>(hb, csr, offs, deg, dinv,
                                                          Whi2, Wlo2, b2, out);
}